// Round 9
// baseline (335.068 us; speedup 1.0000x reference)
//
#include <hip/hip_runtime.h>
#include <math.h>

#define NPTS    131072
#define FEAT    64
#define KCLUS   2048
#define CHUNKC  256      // clusters staged per LDS chunk (== blockDim)
#define NCHUNK  (KCLUS / CHUNKC)   // 8
#define PPW     32       // points per wave (2 MFMA row-tiles)
#define WPB     4        // waves per 256-thread block (wave = 64 on CDNA!)
#define PPB     (PPW * WPB)   // 128 points per block
#define CANDC   10       // per-lane register candidate slots
#define CG      32       // scatter: clusters per block

typedef __attribute__((ext_vector_type(8))) short frag_ab;   // 8 bf16
typedef __attribute__((ext_vector_type(4))) float frag_cd;   // 4 fp32 acc

// fp32 -> bf16 RNE
__device__ __forceinline__ short f2bf(float f) {
    unsigned u = __float_as_uint(f);
    u += 0x7FFFu + ((u >> 16) & 1u);
    return (short)(u >> 16);
}

// Exact fp32 distance term (cn - 2 x.c): IDENTICAL single-chain FMA order to
// all prior proven rounds (matches numpy argmin on this data, absmax 0 x14).
__device__ __forceinline__ float exact_dist(const float* __restrict__ x,
                                            const float* __restrict__ c,
                                            float cnv, int p, int kk) {
    const float4* xr4 = (const float4*)&x[(size_t)p * FEAT];
    const float4* cr4 = (const float4*)&c[(size_t)kk * FEAT];
    float s = 0.f;
#pragma unroll
    for (int j = 0; j < 16; ++j) {
        float4 a4 = xr4[j], b4 = cr4[j];
        s = fmaf(a4.x, b4.x, s); s = fmaf(a4.y, b4.y, s);
        s = fmaf(a4.z, b4.z, s); s = fmaf(a4.w, b4.w, s);
    }
    return fmaf(-2.f, s, cnv);
}

// ---------------------------------------------------------------------------
// cprep: exact fp32 cnorm, cbs_t = bf16(-2c) part-major [part=f/8][k][8]
// (proven layout).  r9: also zeroes sums/counts/tickets (replaces the
// hipMemsetAsync dispatch; stream order guarantees visibility to scatter).
// cmax/atomicMax REMOVED -- assign derives cmax from cnorm (bitwise equal).
// ---------------------------------------------------------------------------
__global__ void cprep_kernel(const float* __restrict__ c, float* __restrict__ cnorm,
                             short* __restrict__ cbs_t,
                             float* __restrict__ sums, int* __restrict__ counts,
                             int* __restrict__ tickets) {
    int k = blockIdx.x * blockDim.x + threadIdx.x;
    if (k >= KCLUS) return;

    // Zero the reduction state (plain stores; visible to scatter via the
    // dispatch boundary).  16 packed-byte tickets cover 64 cluster-groups.
    float4 z = {0.f, 0.f, 0.f, 0.f};
    float4* srow = (float4*)&sums[(size_t)k * FEAT];
#pragma unroll
    for (int j = 0; j < FEAT / 4; ++j) srow[j] = z;
    counts[k] = 0;
    if (k < 16) tickets[k] = 0;

    const float4* row = (const float4*)&c[k * FEAT];
    float s = 0.f;
#pragma unroll
    for (int j = 0; j < 16; ++j) {
        float4 v = row[j];
        s = fmaf(v.x, v.x, s); s = fmaf(v.y, v.y, s);
        s = fmaf(v.z, v.z, s); s = fmaf(v.w, v.w, s);
        short4 b;
        b.x = f2bf(-2.f * v.x); b.y = f2bf(-2.f * v.y);
        b.z = f2bf(-2.f * v.z); b.w = f2bf(-2.f * v.w);
        *(short4*)&cbs_t[((size_t)(j >> 1) * KCLUS + k) * 8 + (j & 1) * 4] = b;
    }
    cnorm[k] = s;
}

// Prefetch one 256-cluster chunk into registers (8 x 16B global loads + norm).
// r0-proven staging path (all alternatives -- gload_lds r1/r2, L2-direct r6 --
// regressed; LDS staging converts 512 ~200cyc L2 reads into ds_reads).
__device__ __forceinline__ void load_chunk(const short* __restrict__ cbs_t,
                                           const float* __restrict__ cnorm,
                                           int k0, int tid,
                                           frag_ab pre[8], float* cnpre) {
#pragma unroll
    for (int p8 = 0; p8 < 8; ++p8)
        pre[p8] = *(const frag_ab*)&cbs_t[((size_t)p8 * KCLUS + k0 + tid) * 8];
    *cnpre = cnorm[k0 + tid];
}

// ---------------------------------------------------------------------------
// Assign: r0-VERBATIM hot loops (proven 124-127 us, absmax 0; six structural
// variants all regressed).  Only change: cmax computed from cnorm in-kernel
// (sqrt monotone => sqrtf(max cnorm) == old atomicMax of sqrtf -- bitwise
// identical threshold), removing the cmax input and its memset dependency.
// ---------------------------------------------------------------------------
__global__ __launch_bounds__(256) void assign_kernel(
    const float* __restrict__ x, const float* __restrict__ c,
    const short* __restrict__ cbs_t, const float* __restrict__ cnorm,
    float* __restrict__ out_assign, unsigned short* __restrict__ a16)
{
    __shared__ short csh[8 * CHUNKC * 8];   // 32 KB part-major staging
    __shared__ float cnsh[CHUNKC];          // 1 KB

    const int tid = threadIdx.x, wv = tid >> 6, lane = tid & 63;
    const int col = lane & 15, q = lane >> 4;
    const int pt0 = blockIdx.x * PPB + wv * PPW;

    // A-frags (proven layout) + inline row norms (proven butterfly over lane
    // bits 16/32: lane's 16 feats of row rt*16+col -> full norm).
    frag_ab A[2][2];
    float nrm[2];
#pragma unroll
    for (int rt = 0; rt < 2; ++rt) {
        float ps = 0.f;
#pragma unroll
        for (int kh = 0; kh < 2; ++kh) {
            const float4* xp = (const float4*)&x[(size_t)(pt0 + rt * 16 + col) * FEAT + kh * 32 + q * 8];
            float4 v0 = xp[0], v1 = xp[1];
            frag_ab a;
            a[0] = f2bf(v0.x); a[1] = f2bf(v0.y); a[2] = f2bf(v0.z); a[3] = f2bf(v0.w);
            a[4] = f2bf(v1.x); a[5] = f2bf(v1.y); a[6] = f2bf(v1.z); a[7] = f2bf(v1.w);
            A[rt][kh] = a;
            ps = fmaf(v0.x, v0.x, ps); ps = fmaf(v0.y, v0.y, ps);
            ps = fmaf(v0.z, v0.z, ps); ps = fmaf(v0.w, v0.w, ps);
            ps = fmaf(v1.x, v1.x, ps); ps = fmaf(v1.y, v1.y, ps);
            ps = fmaf(v1.z, v1.z, ps); ps = fmaf(v1.w, v1.w, ps);
        }
        ps += __shfl_xor(ps, 16);
        ps += __shfl_xor(ps, 32);
        nrm[rt] = sqrtf(ps);
    }

    float m[2][4];
#pragma unroll
    for (int rt = 0; rt < 2; ++rt)
#pragma unroll
        for (int r = 0; r < 4; ++r) m[rt][r] = INFINITY;

    frag_ab pre[8];
    float   cnpre;

    // ------------------- PASS 1: approx min (registers only) --------------
    load_chunk(cbs_t, cnorm, 0, tid, pre, &cnpre);
    for (int c8 = 0; c8 < NCHUNK; ++c8) {
        __syncthreads();
#pragma unroll
        for (int p8 = 0; p8 < 8; ++p8)
            *(frag_ab*)&csh[(p8 * CHUNKC + tid) * 8] = pre[p8];
        cnsh[tid] = cnpre;
        __syncthreads();
        if (c8 < NCHUNK - 1)
            load_chunk(cbs_t, cnorm, (c8 + 1) * CHUNKC, tid, pre, &cnpre);  // overlaps compute

#pragma unroll 4
        for (int ct = 0; ct < CHUNKC / 16; ++ct) {
            const int lc = ct * 16 + col;
            frag_ab b0 = *(const frag_ab*)&csh[(q * CHUNKC + lc) * 8];
            frag_ab b1 = *(const frag_ab*)&csh[((4 + q) * CHUNKC + lc) * 8];
            const float cnv = cnsh[lc];
#pragma unroll
            for (int rt = 0; rt < 2; ++rt) {
                frag_cd acc = {cnv, cnv, cnv, cnv};
                acc = __builtin_amdgcn_mfma_f32_16x16x32_bf16(A[rt][0], b0, acc, 0, 0, 0);
                acc = __builtin_amdgcn_mfma_f32_16x16x32_bf16(A[rt][1], b1, acc, 0, 0, 0);
                m[rt][0] = fminf(m[rt][0], acc[0]);
                m[rt][1] = fminf(m[rt][1], acc[1]);
                m[rt][2] = fminf(m[rt][2], acc[2]);
                m[rt][3] = fminf(m[rt][3], acc[3]);
            }
        }
    }

    // cmax = sqrt(max_k cnorm) -- per-wave strided max + butterfly; bitwise
    // identical to the old atomicMax(sqrtf) result (monotone sqrt, exact max).
    float cmv = 0.f;
#pragma unroll
    for (int j = 0; j < KCLUS / 64; ++j)
        cmv = fmaxf(cmv, cnorm[j * 64 + lane]);
#pragma unroll
    for (int mask = 1; mask <= 32; mask <<= 1)
        cmv = fmaxf(cmv, __shfl_xor(cmv, mask));
    const float cmax = sqrtf(cmv);

    // Threshold: m~ + 0.034*||x||*cmax >= m~ + 2*eps_bf16 (proven margin).
    float t[2][4];
#pragma unroll
    for (int rt = 0; rt < 2; ++rt)
#pragma unroll
        for (int r = 0; r < 4; ++r) {
            float mm = m[rt][r];
            mm = fminf(mm, __shfl_xor(mm, 1));
            mm = fminf(mm, __shfl_xor(mm, 2));
            mm = fminf(mm, __shfl_xor(mm, 4));
            mm = fminf(mm, __shfl_xor(mm, 8));
            float xnp = __shfl(nrm[rt], q * 4 + r);   // lane q*4+r holds that row's norm
            t[rt][r] = mm + 0.034f * xnp * cmax;
        }

    // ------------------- PASS 2: per-lane register capture -----------------
    unsigned codes[CANDC];
    int ccnt = 0;

    load_chunk(cbs_t, cnorm, 0, tid, pre, &cnpre);
    for (int c8 = 0; c8 < NCHUNK; ++c8) {
        __syncthreads();
#pragma unroll
        for (int p8 = 0; p8 < 8; ++p8)
            *(frag_ab*)&csh[(p8 * CHUNKC + tid) * 8] = pre[p8];
        cnsh[tid] = cnpre;
        __syncthreads();
        if (c8 < NCHUNK - 1)
            load_chunk(cbs_t, cnorm, (c8 + 1) * CHUNKC, tid, pre, &cnpre);

        const int k0 = c8 * CHUNKC;
#pragma unroll 2
        for (int ct = 0; ct < CHUNKC / 16; ++ct) {
            const int lc = ct * 16 + col;
            frag_ab b0 = *(const frag_ab*)&csh[(q * CHUNKC + lc) * 8];
            frag_ab b1 = *(const frag_ab*)&csh[((4 + q) * CHUNKC + lc) * 8];
            const float cnv = cnsh[lc];
            const int kk = k0 + lc;
#pragma unroll
            for (int rt = 0; rt < 2; ++rt) {
                frag_cd acc = {cnv, cnv, cnv, cnv};
                acc = __builtin_amdgcn_mfma_f32_16x16x32_bf16(A[rt][0], b0, acc, 0, 0, 0);
                acc = __builtin_amdgcn_mfma_f32_16x16x32_bf16(A[rt][1], b1, acc, 0, 0, 0);
#pragma unroll
                for (int r = 0; r < 4; ++r) {
                    if (acc[r] <= t[rt][r]) {   // rare
                        unsigned code = ((unsigned)(rt * 16 + q * 4 + r) << 11) | (unsigned)kk;
#pragma unroll
                        for (int s = 0; s < CANDC; ++s)   // register-file push
                            if (s == ccnt) codes[s] = code;
                        ccnt++;
                    }
                }
            }
        }
    }

    // ------------------- exact refine (per-lane, registers) ----------------
    const bool anyovf = __any(ccnt > CANDC);

    if (!anyovf) {
        float bestd[2][4];
        int   bestk[2][4];
#pragma unroll
        for (int rt = 0; rt < 2; ++rt)
#pragma unroll
            for (int r = 0; r < 4; ++r) { bestd[rt][r] = INFINITY; bestk[rt][r] = 0x7fffffff; }

        for (int i = 0; i < CANDC; ++i) {
            if (i < ccnt) {
                unsigned code = codes[i];
                int pl = (int)(code >> 11), kk = (int)(code & 2047u);
                float e = exact_dist(x, c, cnorm[kk], pt0 + pl, kk);
                int crt = pl >> 4, cr = pl & 3;
#pragma unroll
                for (int rt = 0; rt < 2; ++rt)
#pragma unroll
                    for (int r = 0; r < 4; ++r)
                        if (crt == rt && cr == r &&
                            (e < bestd[rt][r] || (e == bestd[rt][r] && kk < bestk[rt][r]))) {
                            bestd[rt][r] = e; bestk[rt][r] = kk;
                        }
            }
        }

        // Proven cross-lane (d,k) reduce + col==0 writes (float4 + ushort4).
#pragma unroll
        for (int rt = 0; rt < 2; ++rt) {
#pragma unroll
            for (int r = 0; r < 4; ++r) {
                float bd = bestd[rt][r]; int bk = bestk[rt][r];
#pragma unroll
                for (int mask = 1; mask <= 8; mask <<= 1) {
                    float od = __shfl_xor(bd, mask);
                    int   ok = __shfl_xor(bk, mask);
                    if (od < bd || (od == bd && ok < bk)) { bd = od; bk = ok; }
                }
                bestd[rt][r] = bd; bestk[rt][r] = bk;
            }
            if (col == 0) {
                float4 w = { (float)bestk[rt][0], (float)bestk[rt][1],
                             (float)bestk[rt][2], (float)bestk[rt][3] };
                *(float4*)&out_assign[pt0 + rt * 16 + q * 4] = w;
                ushort4 u = { (unsigned short)bestk[rt][0], (unsigned short)bestk[rt][1],
                              (unsigned short)bestk[rt][2], (unsigned short)bestk[rt][3] };
                *(ushort4*)&a16[pt0 + rt * 16 + q * 4] = u;
            }
        }
    } else {
        // Overflow (rare): whole-wave fully-exact argmin, no thresholds.
        for (int pp = 0; pp < PPW; ++pp) {
            const int p = pt0 + pp;
            float bd = INFINITY; int bk = 0x7fffffff;
            for (int kk = lane; kk < KCLUS; kk += 64) {
                float e = exact_dist(x, c, cnorm[kk], p, kk);
                if (e < bd || (e == bd && kk < bk)) { bd = e; bk = kk; }
            }
#pragma unroll
            for (int mask = 1; mask <= 32; mask <<= 1) {
                float od = __shfl_xor(bd, mask);
                int   ok = __shfl_xor(bk, mask);
                if (od < bd || (od == bd && ok < bk)) { bd = od; bk = ok; }
            }
            if (lane == 0) {
                out_assign[p] = (float)bk;
                a16[p] = (unsigned short)bk;
            }
        }
    }
}

// ---------------------------------------------------------------------------
// Scatter + FUSED update, r9: r8's CG=32 scatter body (absmax-0-proven),
// then a per-cg arrival ticket (byte-packed counters, device-scope RMW):
// the 8th slice-block for a cluster-group reads the now-complete sums/counts
// with agent-scope coherent loads (XCD-safe) and writes the lerp -- exact
// same float expression as the old update_kernel.  Removes one dispatch.
// ---------------------------------------------------------------------------
__global__ void scatter_kernel(const float* __restrict__ x,
                               const unsigned short* __restrict__ a16,
                               const float* __restrict__ c,
                               float* __restrict__ sums, int* __restrict__ counts,
                               int* __restrict__ tickets,
                               float* __restrict__ out_upd) {
    __shared__ float wsum[4][CG][64];   // 32 KB, per-wave private
    __shared__ int   wcnt[4][CG];
    __shared__ int   lastFlag;

    const int tid = threadIdx.x, wv = tid >> 6, lane = tid & 63;
    const int cg = blockIdx.x;
    const int c0 = cg * CG;

    for (int idx = tid; idx < 4 * CG * 64; idx += 256) ((float*)wsum)[idx] = 0.f;
    if (tid < 4 * CG) ((int*)wcnt)[tid] = 0;
    __syncthreads();

    const int base = blockIdx.y * 16384 + wv * 4096;
#pragma unroll 1
    for (int it = 0; it < 64; ++it) {
        const int pbase = base + it * 64;
        int a = (int)a16[pbase + lane];                    // coalesced 128B
        unsigned long long mask = __ballot(a >= c0 && a < c0 + CG);
        while (mask) {
            int j = __ffsll((long long)mask) - 1;
            mask &= mask - 1;
            int cl = __shfl(a, j) - c0;
            float xv = x[(size_t)(pbase + j) * FEAT + lane];  // coalesced 256B row
            wsum[wv][cl][lane] += xv;                         // own slice: no race
            if (lane == 0) wcnt[wv][cl] += 1;
        }
    }
    __syncthreads();

    for (int idx = tid; idx < CG * 64; idx += 256) {
        int cl = idx >> 6, ln = idx & 63;
        float s = wsum[0][cl][ln] + wsum[1][cl][ln] + wsum[2][cl][ln] + wsum[3][cl][ln];
        atomicAdd(&sums[(size_t)(c0 + cl) * FEAT + ln], s);
    }
    if (tid < CG) {
        int cc = wcnt[0][tid] + wcnt[1][tid] + wcnt[2][tid] + wcnt[3][tid];
        if (cc) atomicAdd(&counts[c0 + tid], cc);
    }

    // ---- fused update: last-arriving slice-block for this cg does the lerp.
    __threadfence();          // release this block's adds (device scope)
    __syncthreads();          // all threads' adds issued+fenced before ticket
    if (tid == 0) {
        const int word = cg >> 2, sh = (cg & 3) * 8;
        int old = __hip_atomic_fetch_add(&tickets[word], 1 << sh,
                                         __ATOMIC_ACQ_REL, __HIP_MEMORY_SCOPE_AGENT);
        lastFlag = (((old >> sh) & 0xff) == 7);   // 8th arrival (byte counter)
    }
    __syncthreads();
    if (lastFlag) {
        __threadfence();      // acquire side
        for (int idx = tid; idx < CG * FEAT; idx += 256) {
            int gi = c0 * FEAT + idx;
            int gk = c0 + (idx >> 6);
            float s = __hip_atomic_load(&sums[gi], __ATOMIC_RELAXED,
                                        __HIP_MEMORY_SCOPE_AGENT);
            int cnt = __hip_atomic_load(&counts[gk], __ATOMIC_RELAXED,
                                        __HIP_MEMORY_SCOPE_AGENT);
            float cv = c[gi];
            float nc = (cnt > 0) ? (s / (float)cnt) : cv;   // == update_kernel
            out_upd[gi] = 0.99f * cv + 0.01f * nc;
        }
    }
}

extern "C" void kernel_launch(void* const* d_in, const int* in_sizes, int n_in,
                              void* d_out, int out_size, void* d_ws, size_t ws_size,
                              hipStream_t stream) {
    const float* x = (const float*)d_in[0];
    const float* c = (const float*)d_in[1];

    float* out        = (float*)d_out;
    float* out_assign = out;          // [0, N): assignments as float
    float* out_upd    = out + NPTS;   // [N, N + K*FEAT)

    // Workspace ~1.06 MB (identical footprint to prior rounds).
    char* ws = (char*)d_ws;
    constexpr size_t O_CNORM = 0;                       // 8 KB
    constexpr size_t O_CBS   = 8192;                    // 256 KB
    constexpr size_t O_TICK  = 8192 + 262144;           // 270336, 64 B (16 ints)
    constexpr size_t O_SUMS  = O_TICK + 64;             // 270400, 512 KB
    constexpr size_t O_CNTS  = O_SUMS + 524288;         // 794688, 8 KB
    constexpr size_t O_A16   = O_CNTS + 8192;           // 802880, 256 KB

    float*    cnorm  = (float*)(ws + O_CNORM);
    short*    cbs_t  = (short*)(ws + O_CBS);
    int*      tickets= (int*)(ws + O_TICK);
    float*    sums   = (float*)(ws + O_SUMS);
    int*      counts = (int*)(ws + O_CNTS);
    unsigned short* a16 = (unsigned short*)(ws + O_A16);

    // 3 dispatches (was 5): cprep (also zeroes sums/counts/tickets) ->
    // assign (r0-verbatim hot loops) -> scatter (+fused update).
    cprep_kernel<<<KCLUS / 64, 64, 0, stream>>>(c, cnorm, cbs_t,
                                                sums, counts, tickets);
    assign_kernel<<<NPTS / PPB, 256, 0, stream>>>(x, c, cbs_t, cnorm,
                                                  out_assign, a16);
    scatter_kernel<<<dim3(KCLUS / CG, 8), 256, 0, stream>>>(x, a16, c, sums,
                                                            counts, tickets,
                                                            out_upd);
}